// Round 8
// baseline (150.677 us; speedup 1.0000x reference)
//
#include <hip/hip_runtime.h>

#define NB   500000   // B: rule neurons
#define NW   8        // W: weights per rule
#define ND   16       // D: per-neuron dim

// fast tanh: 1 - 2/(exp(2x)+1); exact saturation at +-inf, ~1e-6 abs err
__device__ __forceinline__ float fast_tanh(float x) {
    float e = __expf(2.0f * x);
    return 1.0f - 2.0f * __builtin_amdgcn_rcpf(e + 1.0f);
}

// 2 neurons per thread, 4 threads per neuron (thread owns one float4 of D=16).
// 256-thread block = 64 neuron slots x 2 neurons = 128 neurons/block.
// Pair is (b, b+64) so each wave's loads/stores stay contiguous (16 neurons
// x 64B = 1KB per instruction). 16 gathers in flight before any consume.
__global__ __launch_bounds__(256) void wrl_kernel(
    const float* __restrict__ values,   // [N_SRC, 16]
    const float* __restrict__ weights,  // [8, 16]
    const int*   __restrict__ indices,  // [8, B]
    float* __restrict__ out)            // [B, 16]
{
    const int t  = threadIdx.x;
    const int dq = t & 3;
    const int g  = t >> 2;                  // 0..63: neuron slot
    const int b0 = blockIdx.x * 128 + g;    // first neuron
    const int b1 = b0 + 64;                 // second neuron
    const int b0c = b0 < NB ? b0 : NB - 1;  // clamped for loads
    const int b1c = b1 < NB ? b1 : NB - 1;

    // weights into registers: 8 x float4 (broadcast loads, L1-resident)
    float4 wreg[NW];
#pragma unroll
    for (int w = 0; w < NW; ++w)
        wreg[w] = *reinterpret_cast<const float4*>(weights + w * ND + dq * 4);

    // 16 index loads up front
    int idx0[NW], idx1[NW];
#pragma unroll
    for (int w = 0; w < NW; ++w) idx0[w] = indices[w * NB + b0c];
#pragma unroll
    for (int w = 0; w < NW; ++w) idx1[w] = indices[w * NB + b1c];

    // 16 gathers in flight before any FMA consumes them
    float4 val0[NW], val1[NW];
#pragma unroll
    for (int w = 0; w < NW; ++w)
        val0[w] = *reinterpret_cast<const float4*>(values + (size_t)idx0[w] * ND + dq * 4);
#pragma unroll
    for (int w = 0; w < NW; ++w)
        val1[w] = *reinterpret_cast<const float4*>(values + (size_t)idx1[w] * ND + dq * 4);

    float4 a0 = make_float4(0.f, 0.f, 0.f, 0.f);
    float4 a1 = make_float4(0.f, 0.f, 0.f, 0.f);
#pragma unroll
    for (int w = 0; w < NW; ++w) {
        a0.x += val0[w].x * wreg[w].x;  a0.y += val0[w].y * wreg[w].y;
        a0.z += val0[w].z * wreg[w].z;  a0.w += val0[w].w * wreg[w].w;
        a1.x += val1[w].x * wreg[w].x;  a1.y += val1[w].y * wreg[w].y;
        a1.z += val1[w].z * wreg[w].z;  a1.w += val1[w].w * wreg[w].w;
    }

    if (b0 < NB) {
        float4 o;
        o.x = fast_tanh(a0.x); o.y = fast_tanh(a0.y);
        o.z = fast_tanh(a0.z); o.w = fast_tanh(a0.w);
        *reinterpret_cast<float4*>(out + (size_t)b0 * ND + dq * 4) = o;
    }
    if (b1 < NB) {
        float4 o;
        o.x = fast_tanh(a1.x); o.y = fast_tanh(a1.y);
        o.z = fast_tanh(a1.z); o.w = fast_tanh(a1.w);
        *reinterpret_cast<float4*>(out + (size_t)b1 * ND + dq * 4) = o;
    }
}

extern "C" void kernel_launch(void* const* d_in, const int* in_sizes, int n_in,
                              void* d_out, int out_size, void* d_ws, size_t ws_size,
                              hipStream_t stream) {
    const float* values  = (const float*)d_in[0];
    const float* weights = (const float*)d_in[1];
    const int*   indices = (const int*)d_in[2];
    float* out = (float*)d_out;

    const int blocks = (NB + 127) / 128;   // 3907 blocks, 128 neurons each
    wrl_kernel<<<blocks, 256, 0, stream>>>(values, weights, indices, out);
}